// Round 1
// baseline (4216.739 us; speedup 1.0000x reference)
//
#include <hip/hip_runtime.h>

typedef unsigned short ushort_t;
typedef unsigned int uint32;

#define SB 16
#define SS 2048
#define SD 256
#define KAPPA 4.8828125e-6f   // 0.01 * 2/(16*256)

__device__ __forceinline__ ushort_t f2bf(float f) {
  uint32 u = __float_as_uint(f);
  u = (u + 0x7FFFu + ((u >> 16) & 1u)) >> 16;
  return (ushort_t)u;
}

// ---------------- prep: train/state (bf16, [t][b][d] layout) ----------------
__global__ __launch_bounds__(256) void prep_kernel(
    const float* __restrict__ x, const float* __restrict__ noise,
    const float* __restrict__ a1,
    ushort_t* __restrict__ train, ushort_t* __restrict__ state) {
  size_t i4 = (size_t)blockIdx.x * 256 + threadIdx.x;  // one float4
  size_t base = i4 * 4;
  int d = (int)(base & 255);
  int t = (int)((base >> 8) & 2047);
  int b = (int)(base >> 19);
  float4 xv = *(const float4*)(x + base);
  float4 nv = *(const float4*)(noise + base);
  float4 av = *(const float4*)(a1 + d);
  float m0 = tanhf(av.x * xv.x);
  float m1 = tanhf(av.y * xv.y);
  float m2 = tanhf(av.z * xv.z);
  float m3 = tanhf(av.w * xv.w);
  size_t dst = ((size_t)t * SB + b) * SD + d;
  ushort4 tr, st;
  tr.x = f2bf(m0 + nv.x); tr.y = f2bf(m1 + nv.y);
  tr.z = f2bf(m2 + nv.z); tr.w = f2bf(m3 + nv.w);
  st.x = f2bf(m0); st.y = f2bf(m1); st.z = f2bf(m2); st.w = f2bf(m3);
  *(ushort4*)(train + dst) = tr;
  *(ushort4*)(state + dst) = st;
}

// ---------------- gram: G[t][b][b'] = state_t[b] . train_t[b'] ----------------
__global__ __launch_bounds__(256) void gram_kernel(
    const ushort_t* __restrict__ train, const ushort_t* __restrict__ state,
    float* __restrict__ G) {
  __shared__ float Tr[16][260];
  __shared__ float St[16][260];
  const int t = blockIdx.x;
  const int tid = threadIdx.x;
#pragma unroll
  for (int v = 0; v < 2; ++v) {
    int flat8 = tid + v * 256;           // 0..511
    int b = flat8 >> 5;
    int d8 = (flat8 & 31) * 8;
    uint4 tv = *(const uint4*)(train + ((size_t)t * SB + b) * SD + d8);
    uint4 sv = *(const uint4*)(state + ((size_t)t * SB + b) * SD + d8);
    uint32 tw[4] = {tv.x, tv.y, tv.z, tv.w};
    uint32 sw[4] = {sv.x, sv.y, sv.z, sv.w};
#pragma unroll
    for (int e = 0; e < 4; ++e) {
      Tr[b][d8 + 2 * e]     = __uint_as_float(tw[e] << 16);
      Tr[b][d8 + 2 * e + 1] = __uint_as_float(tw[e] & 0xFFFF0000u);
      St[b][d8 + 2 * e]     = __uint_as_float(sw[e] << 16);
      St[b][d8 + 2 * e + 1] = __uint_as_float(sw[e] & 0xFFFF0000u);
    }
  }
  __syncthreads();
  int b = tid >> 4, bp = tid & 15;
  float s = 0.f;
#pragma unroll 8
  for (int k = 0; k < 256; k += 4) {
    float4 sv = *(const float4*)&St[b][k];
    float4 tv = *(const float4*)&Tr[bp][k];
    s += sv.x * tv.x + sv.y * tv.y + sv.z * tv.z + sv.w * tv.w;
  }
  G[(size_t)t * 256 + tid] = s;
}

// ---------------- ff path: out = u .* (v @ Wp^T) ----------------
__global__ __launch_bounds__(256) void ff_kernel(
    const float* __restrict__ x, const float* __restrict__ a2,
    const float* __restrict__ Wp, const float* __restrict__ ffa,
    const float* __restrict__ ffb, const float* __restrict__ ffg_,
    const float* __restrict__ ffe_, float* __restrict__ out) {
  __shared__ float As[32][68];   // As[k][m] = v
  __shared__ float Bs[32][68];   // Bs[k][n] = Wp[n][k]
  const int tid = threadIdx.x;
  const int gm0 = blockIdx.x * 64;
  const int gn0 = blockIdx.y * 64;
  const int tm = tid & 15, tn = tid >> 4;
  const int lr = tid & 63;
  const int lq = tid >> 6;
  float acc[4][4];
#pragma unroll
  for (int i = 0; i < 4; i++)
#pragma unroll
    for (int j = 0; j < 4; j++) acc[i][j] = 0.f;

  for (int k0 = 0; k0 < 256; k0 += 32) {
    {
      const float* xp = x + (size_t)(gm0 + lr) * 256 + k0 + lq * 8;
      float4 v0 = *(const float4*)(xp);
      float4 v1 = *(const float4*)(xp + 4);
      const float* ap = a2 + k0 + lq * 8;
      float4 a0 = *(const float4*)(ap);
      float4 a1v = *(const float4*)(ap + 4);
      As[lq * 8 + 0][lr] = tanhf(a0.x * v0.x);
      As[lq * 8 + 1][lr] = tanhf(a0.y * v0.y);
      As[lq * 8 + 2][lr] = tanhf(a0.z * v0.z);
      As[lq * 8 + 3][lr] = tanhf(a0.w * v0.w);
      As[lq * 8 + 4][lr] = tanhf(a1v.x * v1.x);
      As[lq * 8 + 5][lr] = tanhf(a1v.y * v1.y);
      As[lq * 8 + 6][lr] = tanhf(a1v.z * v1.z);
      As[lq * 8 + 7][lr] = tanhf(a1v.w * v1.w);
      const float* wp = Wp + (size_t)(gn0 + lr) * 256 + k0 + lq * 8;
      float4 w0 = *(const float4*)(wp);
      float4 w1 = *(const float4*)(wp + 4);
      Bs[lq * 8 + 0][lr] = w0.x; Bs[lq * 8 + 1][lr] = w0.y;
      Bs[lq * 8 + 2][lr] = w0.z; Bs[lq * 8 + 3][lr] = w0.w;
      Bs[lq * 8 + 4][lr] = w1.x; Bs[lq * 8 + 5][lr] = w1.y;
      Bs[lq * 8 + 6][lr] = w1.z; Bs[lq * 8 + 7][lr] = w1.w;
    }
    __syncthreads();
#pragma unroll
    for (int k = 0; k < 32; ++k) {
      float4 av4 = *(const float4*)&As[k][tm * 4];
      float4 bv4 = *(const float4*)&Bs[k][tn * 4];
      float a[4] = {av4.x, av4.y, av4.z, av4.w};
      float b[4] = {bv4.x, bv4.y, bv4.z, bv4.w};
#pragma unroll
      for (int i = 0; i < 4; i++)
#pragma unroll
        for (int j = 0; j < 4; j++) acc[i][j] += a[i] * b[j];
    }
    __syncthreads();
  }
  const float ga = ffg_[0], et = ffe_[0];
#pragma unroll
  for (int ii = 0; ii < 4; ++ii) {
    int row = gm0 + tm * 4 + ii;
    int col = gn0 + tn * 4;
    float4 xv = *(const float4*)(x + (size_t)row * 256 + col);
    float4 fa = *(const float4*)(ffa + col);
    float4 fb = *(const float4*)(ffb + col);
    float4 a2v = *(const float4*)(a2 + col);
    float xs[4] = {xv.x, xv.y, xv.z, xv.w};
    float fas[4] = {fa.x, fa.y, fa.z, fa.w};
    float fbs[4] = {fb.x, fb.y, fb.z, fb.w};
    float a2s[4] = {a2v.x, a2v.y, a2v.z, a2v.w};
    float res[4];
#pragma unroll
    for (int j = 0; j < 4; ++j) {
      float v = tanhf(a2s[j] * xs[j]);
      float z = fas[j] * v;
      float gelu = 0.5f * z * (1.0f + erff(z * 0.70710678118654752f));
      float u = ga * gelu + et * sinf(fbs[j] * v);
      res[j] = u * acc[ii][j];
    }
    float4 o; o.x = res[0]; o.y = res[1]; o.z = res[2]; o.w = res[3];
    *(float4*)(out + (size_t)row * 256 + col) = o;
  }
}

// ---------------- scan: row-partitioned persistent TTT ----------------
__device__ __forceinline__ void issue_pf(const ushort_t* train, const ushort_t* state,
                                         const float* G, int t, int tid,
                                         uint4 (&pf)[4], float4& gpf) {
#pragma unroll
  for (int v = 0; v < 4; ++v) {
    int flat8 = tid + (v & 1) * 256;     // 0..511
    int b = flat8 >> 5;
    int d8 = (flat8 & 31) * 8;
    const ushort_t* src = (v < 2) ? train : state;
    pf[v] = *(const uint4*)(src + ((size_t)t * SB + b) * SD + d8);
  }
  if (tid < 64) gpf = *(const float4*)(G + (size_t)t * 256 + tid * 4);
}

__global__ __launch_bounds__(256, 1) void scan_kernel(
    const ushort_t* __restrict__ train, const ushort_t* __restrict__ state,
    const float* __restrict__ G, const float* __restrict__ Wttt,
    float* __restrict__ out) {
  __shared__ float Xs[2][32][260];   // rows 0..15 train, 16..31 state
  __shared__ float Wl[4][260];       // own 4 rows of W, f32 master
  __shared__ float Pred[32][4][2];   // K-half partials of [train;state]@W^T
  __shared__ float diffs[16][4];
  __shared__ float Qv[16][4];
  __shared__ float Gs[2][256];
  __shared__ float Oacc[16][16][4];  // [step%16][b][r]

  const int tid = threadIdx.x;
  const int wg = blockIdx.x;         // owns W rows wg*4 .. wg*4+3

  for (int i = tid; i < 4 * 256; i += 256) {
    int r = i >> 8, d2 = i & 255;
    Wl[r][d2] = Wttt[(size_t)(wg * 4 + r) * 256 + d2];
  }

  uint4 pf[4];
  float4 gpf;
  issue_pf(train, state, G, 0, tid, pf, gpf);

  for (int t = 0; t < SS; ++t) {
    const int buf = t & 1;
    // ---- stage prefetched step into LDS (bf16 -> f32) ----
#pragma unroll
    for (int v = 0; v < 4; ++v) {
      int flat8 = tid + (v & 1) * 256;
      int b = flat8 >> 5;
      int d8 = (flat8 & 31) * 8;
      int row = (v < 2) ? b : 16 + b;
      uint32 w[4] = {pf[v].x, pf[v].y, pf[v].z, pf[v].w};
#pragma unroll
      for (int e = 0; e < 4; ++e) {
        Xs[buf][row][d8 + 2 * e]     = __uint_as_float(w[e] << 16);
        Xs[buf][row][d8 + 2 * e + 1] = __uint_as_float(w[e] & 0xFFFF0000u);
      }
    }
    if (tid < 64) *(float4*)&Gs[buf][tid * 4] = gpf;
    __syncthreads();

    if (t + 1 < SS) issue_pf(train, state, G, t + 1, tid, pf, gpf);

    // ---- phase A: P/Q = [train;state] @ Wown^T  (K split in halves) ----
    {
      const int j = tid & 31;
      const int d1r = (tid >> 5) & 3;
      const int kh = tid >> 7;
      const float* xr = &Xs[buf][j][kh * 128];
      const float* wr = &Wl[d1r][kh * 128];
      float acc = 0.f;
#pragma unroll 8
      for (int k = 0; k < 128; k += 4) {
        float4 xv = *(const float4*)(xr + k);
        float4 wv = *(const float4*)(wr + k);
        acc += xv.x * wv.x + xv.y * wv.y + xv.z * wv.z + xv.w * wv.w;
      }
      Pred[j][d1r][kh] = acc;
    }
    __syncthreads();

    // ---- combine: diff = P_train - state_own ; Q = P_state ----
    if (tid < 64) {
      int b = tid & 15, r = tid >> 4;
      diffs[b][r] = Pred[b][r][0] + Pred[b][r][1] - Xs[buf][16 + b][wg * 4 + r];
    } else if (tid < 128) {
      int q = tid - 64;
      int b = q & 15, r = q >> 4;
      Qv[b][r] = Pred[16 + b][r][0] + Pred[16 + b][r][1];
    }
    __syncthreads();

    // ---- phase B: W -= kappa * diff^T @ train (thread owns column d2=tid) ----
    {
      float xcol[16];
#pragma unroll
      for (int b2 = 0; b2 < 16; ++b2) xcol[b2] = Xs[buf][b2][tid];
#pragma unroll
      for (int r2 = 0; r2 < 4; ++r2) {
        float s = 0.f;
#pragma unroll
        for (int b2 = 0; b2 < 16; ++b2) s += diffs[b2][r2] * xcol[b2];
        Wl[r2][tid] -= KAPPA * s;
      }
    }

    // ---- phase C: out = Q - kappa * G_t @ diff  (uses pre-update W identity) ----
    if (tid < 64) {
      int b = tid & 15, r = tid >> 4;
      float s = 0.f;
#pragma unroll
      for (int bp = 0; bp < 16; ++bp) s += Gs[buf][b * 16 + bp] * diffs[bp][r];
      Oacc[t & 15][b][r] = Qv[b][r] - KAPPA * s;
    }
    __syncthreads();

    // ---- dump 16 steps of outputs, float4 per (b,step), add ff-path value ----
    if ((t & 15) == 15) {
      int s_ = tid >> 4, b = tid & 15;
      size_t oi = ((size_t)b * SS + (size_t)(t - 15 + s_)) * SD + wg * 4;
      float4 prev = *(const float4*)(out + oi);
      const float* oa = &Oacc[s_][b][0];
      float4 res;
      res.x = prev.x + oa[0];
      res.y = prev.y + oa[1];
      res.z = prev.z + oa[2];
      res.w = prev.w + oa[3];
      *(float4*)(out + oi) = res;
    }
  }
}

extern "C" void kernel_launch(void* const* d_in, const int* in_sizes, int n_in,
                              void* d_out, int out_size, void* d_ws, size_t ws_size,
                              hipStream_t stream) {
  const float* x     = (const float*)d_in[0];
  const float* noise = (const float*)d_in[1];
  const float* a1    = (const float*)d_in[2];
  const float* a2    = (const float*)d_in[3];
  const float* Wttt  = (const float*)d_in[4];
  const float* Wproj = (const float*)d_in[5];
  const float* ffa   = (const float*)d_in[6];
  const float* ffb   = (const float*)d_in[7];
  const float* ffg   = (const float*)d_in[8];
  const float* ffe   = (const float*)d_in[9];
  float* out = (float*)d_out;

  const size_t N = (size_t)SB * SS * SD;     // 8388608
  ushort_t* train = (ushort_t*)d_ws;
  ushort_t* state = train + N;
  float* G = (float*)(state + N);            // needs 2*16.78MB + 2MB = ~35.6MB ws

  prep_kernel<<<8192, 256, 0, stream>>>(x, noise, a1, train, state);
  gram_kernel<<<2048, 256, 0, stream>>>(train, state, G);
  ff_kernel<<<dim3(512, 4), 256, 0, stream>>>(x, a2, Wproj, ffa, ffb, ffg, ffe, out);
  scan_kernel<<<64, 256, 0, stream>>>(train, state, G, Wttt, out);
}

// Round 2
// 2446.649 us; speedup vs baseline: 1.7235x; 1.7235x over previous
//
#include <hip/hip_runtime.h>

typedef unsigned short ushort_t;
typedef unsigned int uint32;

#define SB 16
#define SS 2048
#define SD 256
#define KAPPA 4.8828125e-6f   // 0.01 * 2/(16*256)
#define XPITCH 264            // ushorts per LDS X row (132 words, ==4 mod 32)

__device__ __forceinline__ ushort_t f2bf(float f) {
  uint32 u = __float_as_uint(f);
  u = (u + 0x7FFFu + ((u >> 16) & 1u)) >> 16;
  return (ushort_t)u;
}
__device__ __forceinline__ float blo(uint32 u) { return __uint_as_float(u << 16); }
__device__ __forceinline__ float bhi(uint32 u) { return __uint_as_float(u & 0xFFFF0000u); }

// ---------------- prep: train/state (bf16, [t][b][d] layout) ----------------
__global__ __launch_bounds__(256) void prep_kernel(
    const float* __restrict__ x, const float* __restrict__ noise,
    const float* __restrict__ a1,
    ushort_t* __restrict__ train, ushort_t* __restrict__ state) {
  size_t i4 = (size_t)blockIdx.x * 256 + threadIdx.x;  // one float4
  size_t base = i4 * 4;
  int d = (int)(base & 255);
  int t = (int)((base >> 8) & 2047);
  int b = (int)(base >> 19);
  float4 xv = *(const float4*)(x + base);
  float4 nv = *(const float4*)(noise + base);
  float4 av = *(const float4*)(a1 + d);
  float m0 = tanhf(av.x * xv.x);
  float m1 = tanhf(av.y * xv.y);
  float m2 = tanhf(av.z * xv.z);
  float m3 = tanhf(av.w * xv.w);
  size_t dst = ((size_t)t * SB + b) * SD + d;
  ushort4 tr, st;
  tr.x = f2bf(m0 + nv.x); tr.y = f2bf(m1 + nv.y);
  tr.z = f2bf(m2 + nv.z); tr.w = f2bf(m3 + nv.w);
  st.x = f2bf(m0); st.y = f2bf(m1); st.z = f2bf(m2); st.w = f2bf(m3);
  *(ushort4*)(train + dst) = tr;
  *(ushort4*)(state + dst) = st;
}

// ---------------- gram: G[t][b][b'] = state_t[b] . train_t[b'] ----------------
__global__ __launch_bounds__(256) void gram_kernel(
    const ushort_t* __restrict__ train, const ushort_t* __restrict__ state,
    float* __restrict__ G) {
  __shared__ float Tr[16][260];
  __shared__ float St[16][260];
  const int t = blockIdx.x;
  const int tid = threadIdx.x;
#pragma unroll
  for (int v = 0; v < 2; ++v) {
    int flat8 = tid + v * 256;           // 0..511
    int b = flat8 >> 5;
    int d8 = (flat8 & 31) * 8;
    uint4 tv = *(const uint4*)(train + ((size_t)t * SB + b) * SD + d8);
    uint4 sv = *(const uint4*)(state + ((size_t)t * SB + b) * SD + d8);
    uint32 tw[4] = {tv.x, tv.y, tv.z, tv.w};
    uint32 sw[4] = {sv.x, sv.y, sv.z, sv.w};
#pragma unroll
    for (int e = 0; e < 4; ++e) {
      Tr[b][d8 + 2 * e]     = blo(tw[e]);
      Tr[b][d8 + 2 * e + 1] = bhi(tw[e]);
      St[b][d8 + 2 * e]     = blo(sw[e]);
      St[b][d8 + 2 * e + 1] = bhi(sw[e]);
    }
  }
  __syncthreads();
  int b = tid >> 4, bp = tid & 15;
  float s = 0.f;
#pragma unroll 8
  for (int k = 0; k < 256; k += 4) {
    float4 sv = *(const float4*)&St[b][k];
    float4 tv = *(const float4*)&Tr[bp][k];
    s += sv.x * tv.x + sv.y * tv.y + sv.z * tv.z + sv.w * tv.w;
  }
  G[(size_t)t * 256 + tid] = s;
}

// ---------------- ff path: out = u .* (v @ Wp^T) ----------------
__global__ __launch_bounds__(256) void ff_kernel(
    const float* __restrict__ x, const float* __restrict__ a2,
    const float* __restrict__ Wp, const float* __restrict__ ffa,
    const float* __restrict__ ffb, const float* __restrict__ ffg_,
    const float* __restrict__ ffe_, float* __restrict__ out) {
  __shared__ float As[32][68];
  __shared__ float Bs[32][68];
  const int tid = threadIdx.x;
  const int gm0 = blockIdx.x * 64;
  const int gn0 = blockIdx.y * 64;
  const int tm = tid & 15, tn = tid >> 4;
  const int lr = tid & 63;
  const int lq = tid >> 6;
  float acc[4][4];
#pragma unroll
  for (int i = 0; i < 4; i++)
#pragma unroll
    for (int j = 0; j < 4; j++) acc[i][j] = 0.f;

  for (int k0 = 0; k0 < 256; k0 += 32) {
    {
      const float* xp = x + (size_t)(gm0 + lr) * 256 + k0 + lq * 8;
      float4 v0 = *(const float4*)(xp);
      float4 v1 = *(const float4*)(xp + 4);
      const float* ap = a2 + k0 + lq * 8;
      float4 a0 = *(const float4*)(ap);
      float4 a1v = *(const float4*)(ap + 4);
      As[lq * 8 + 0][lr] = tanhf(a0.x * v0.x);
      As[lq * 8 + 1][lr] = tanhf(a0.y * v0.y);
      As[lq * 8 + 2][lr] = tanhf(a0.z * v0.z);
      As[lq * 8 + 3][lr] = tanhf(a0.w * v0.w);
      As[lq * 8 + 4][lr] = tanhf(a1v.x * v1.x);
      As[lq * 8 + 5][lr] = tanhf(a1v.y * v1.y);
      As[lq * 8 + 6][lr] = tanhf(a1v.z * v1.z);
      As[lq * 8 + 7][lr] = tanhf(a1v.w * v1.w);
      const float* wp = Wp + (size_t)(gn0 + lr) * 256 + k0 + lq * 8;
      float4 w0 = *(const float4*)(wp);
      float4 w1 = *(const float4*)(wp + 4);
      Bs[lq * 8 + 0][lr] = w0.x; Bs[lq * 8 + 1][lr] = w0.y;
      Bs[lq * 8 + 2][lr] = w0.z; Bs[lq * 8 + 3][lr] = w0.w;
      Bs[lq * 8 + 4][lr] = w1.x; Bs[lq * 8 + 5][lr] = w1.y;
      Bs[lq * 8 + 6][lr] = w1.z; Bs[lq * 8 + 7][lr] = w1.w;
    }
    __syncthreads();
#pragma unroll
    for (int k = 0; k < 32; ++k) {
      float4 av4 = *(const float4*)&As[k][tm * 4];
      float4 bv4 = *(const float4*)&Bs[k][tn * 4];
      float a[4] = {av4.x, av4.y, av4.z, av4.w};
      float b[4] = {bv4.x, bv4.y, bv4.z, bv4.w};
#pragma unroll
      for (int i = 0; i < 4; i++)
#pragma unroll
        for (int j = 0; j < 4; j++) acc[i][j] += a[i] * b[j];
    }
    __syncthreads();
  }
  const float ga = ffg_[0], et = ffe_[0];
#pragma unroll
  for (int ii = 0; ii < 4; ++ii) {
    int row = gm0 + tm * 4 + ii;
    int col = gn0 + tn * 4;
    float4 xv = *(const float4*)(x + (size_t)row * 256 + col);
    float4 fa = *(const float4*)(ffa + col);
    float4 fb = *(const float4*)(ffb + col);
    float4 a2v = *(const float4*)(a2 + col);
    float xs[4] = {xv.x, xv.y, xv.z, xv.w};
    float fas[4] = {fa.x, fa.y, fa.z, fa.w};
    float fbs[4] = {fb.x, fb.y, fb.z, fb.w};
    float a2s[4] = {a2v.x, a2v.y, a2v.z, a2v.w};
    float res[4];
#pragma unroll
    for (int j = 0; j < 4; ++j) {
      float v = tanhf(a2s[j] * xs[j]);
      float z = fas[j] * v;
      float gelu = 0.5f * z * (1.0f + erff(z * 0.70710678118654752f));
      float u = ga * gelu + et * sinf(fbs[j] * v);
      res[j] = u * acc[ii][j];
    }
    float4 o; o.x = res[0]; o.y = res[1]; o.z = res[2]; o.w = res[3];
    *(float4*)(out + (size_t)row * 256 + col) = o;
  }
}

// ---------------- scan: 256 WGs, one W row each ----------------
// Per WG (owns W row `row`):
//   phase A: P[j] = X_j . w  (j=0..15 train -> diff, 16..31 state -> Q)
//   phase B: w[k] -= kappa * sum_b diff[b] * train[b][k]
//   phase C: out[b] = Q[b] - kappa * sum_b' G[t][b][b'] * diff[b']
__global__ __launch_bounds__(256, 1) void scan_kernel(
    const ushort_t* __restrict__ train, const ushort_t* __restrict__ state,
    const float* __restrict__ G, const float* __restrict__ Wttt,
    float* __restrict__ out) {
  __shared__ ushort_t Xs[2][32 * XPITCH];  // rows 0..15 train, 16..31 state
  __shared__ float wrow[SD];               // own W row, f32 master
  __shared__ float Ptl[32 * 9];            // phase-A partials [j][kg], pitch 9
  __shared__ float diffv[16];
  __shared__ float Qv[16];
  __shared__ float Obuf[16][16];           // [step%16][b]

  const int tid = threadIdx.x;
  const int bx = blockIdx.x;
  // XCD-aware swizzle: 32 consecutive rows (two 64B out-lines) per XCD
  const int row = ((bx & 7) << 5) | (bx >> 3);

  wrow[tid] = Wttt[(size_t)row * SD + tid];

  const int srow = tid >> 3;   // 0..31: X row staged AND dotted by this thread
  const int kg   = tid & 7;    // 32-element k-group
  const ushort_t* xbase = (srow < 16 ? train : state) +
                          ((size_t)(srow & 15)) * SD + kg * 32;
  const int gq = tid >> 4;     // for G regs (tid<64): quarter
  const int gb = tid & 15;

  // prefetch t=0
  uint4 c0, c1, c2, c3;
  float4 gc;
  {
    const uint4* gp = (const uint4*)(xbase);
    c0 = gp[0]; c1 = gp[1]; c2 = gp[2]; c3 = gp[3];
    if (tid < 64) gc = *(const float4*)(G + (size_t)gb * 16 + gq * 4);
  }

  for (int t = 0; t < SS; ++t) {
    const int buf = t & 1;
    // ---- stage this step's X into LDS (raw bf16 copy) ----
    {
      ushort_t* d = &Xs[buf][srow * XPITCH + kg * 32];
      *(uint4*)(d)      = c0;
      *(uint4*)(d + 8)  = c1;
      *(uint4*)(d + 16) = c2;
      *(uint4*)(d + 24) = c3;
    }
    // ---- issue prefetch for t+1 into separate regs ----
    uint4 n0, n1, n2, n3;
    float4 gn;
    {
      const int tn_ = (t + 1 < SS) ? (t + 1) : 0;
      const uint4* gp = (const uint4*)(xbase + (size_t)tn_ * (SB * SD));
      n0 = gp[0]; n1 = gp[1]; n2 = gp[2]; n3 = gp[3];
      if (tid < 64) gn = *(const float4*)(G + (size_t)tn_ * 256 + gb * 16 + gq * 4);
    }
    __syncthreads();  // b1: staging visible; wrow(t-1 update) visible

    // ---- phase A: P[srow] partial over own 32 k's, X from registers ----
    {
      float a0 = 0.f, a1 = 0.f, a2 = 0.f, a3 = 0.f;
      const float* wp = &wrow[kg * 32];
      uint4 cc[4] = {c0, c1, c2, c3};
#pragma unroll
      for (int i = 0; i < 4; ++i) {
        float4 w0 = *(const float4*)(wp + i * 8);
        float4 w1 = *(const float4*)(wp + i * 8 + 4);
        uint4 q = cc[i];
        a0 += blo(q.x) * w0.x; a1 += bhi(q.x) * w0.y;
        a2 += blo(q.y) * w0.z; a3 += bhi(q.y) * w0.w;
        a0 += blo(q.z) * w1.x; a1 += bhi(q.z) * w1.y;
        a2 += blo(q.w) * w1.z; a3 += bhi(q.w) * w1.w;
      }
      Ptl[srow * 9 + kg] = (a0 + a1) + (a2 + a3);
    }
    __syncthreads();  // b2: partials ready

    // ---- reduce partials; publish diff (train rows) and Q (state rows) ----
    if (tid < 32) {
      const float* p = &Ptl[tid * 9];
      float s = ((p[0] + p[1]) + (p[2] + p[3])) + ((p[4] + p[5]) + (p[6] + p[7]));
      if (tid < 16) {
        float sown = blo((uint32)Xs[buf][(16 + tid) * XPITCH + row] << 16 >> 16 << 16);
        // (simple form below; keep it readable)
        sown = __uint_as_float(((uint32)Xs[buf][(16 + tid) * XPITCH + row]) << 16);
        diffv[tid] = s - sown;
      } else {
        Qv[tid - 16] = s;
      }
    }
    __syncthreads();  // b3: diff/Q ready

    // ---- phase B: own W column k=tid update ----
    {
      float dv[16];
#pragma unroll
      for (int b = 0; b < 16; ++b) dv[b] = diffv[b];
      float s0 = 0.f, s1 = 0.f;
#pragma unroll
      for (int b = 0; b < 16; b += 2) {
        float x0 = __uint_as_float(((uint32)Xs[buf][b * XPITCH + tid]) << 16);
        float x1 = __uint_as_float(((uint32)Xs[buf][(b + 1) * XPITCH + tid]) << 16);
        s0 += dv[b] * x0;
        s1 += dv[b + 1] * x1;
      }
      wrow[tid] -= KAPPA * (s0 + s1);
    }

    // ---- phase C: out[b] = Q[b] - kappa * sum_b' G[b][b'] diff[b'] ----
    if (tid < 64) {
      float s = gc.x * diffv[gq * 4 + 0] + gc.y * diffv[gq * 4 + 1] +
                gc.z * diffv[gq * 4 + 2] + gc.w * diffv[gq * 4 + 3];
      s += __shfl_xor(s, 16, 64);
      s += __shfl_xor(s, 32, 64);
      if (gq == 0) Obuf[t & 15][gb] = Qv[gb] - KAPPA * s;
    }

    // ---- dump 16 steps of outputs (add onto ff-path values) ----
    if ((t & 15) == 15) {
      __syncthreads();  // b4: Obuf complete
      int s_ = tid >> 4, b = tid & 15;
      size_t oi = ((size_t)b * SS + (size_t)(t - 15 + s_)) * SD + row;
      out[oi] += Obuf[s_][b];
    }

    c0 = n0; c1 = n1; c2 = n2; c3 = n3;
    gc = gn;
  }
}

extern "C" void kernel_launch(void* const* d_in, const int* in_sizes, int n_in,
                              void* d_out, int out_size, void* d_ws, size_t ws_size,
                              hipStream_t stream) {
  const float* x     = (const float*)d_in[0];
  const float* noise = (const float*)d_in[1];
  const float* a1    = (const float*)d_in[2];
  const float* a2    = (const float*)d_in[3];
  const float* Wttt  = (const float*)d_in[4];
  const float* Wproj = (const float*)d_in[5];
  const float* ffa   = (const float*)d_in[6];
  const float* ffb   = (const float*)d_in[7];
  const float* ffg   = (const float*)d_in[8];
  const float* ffe   = (const float*)d_in[9];
  float* out = (float*)d_out;

  const size_t N = (size_t)SB * SS * SD;     // 8388608
  ushort_t* train = (ushort_t*)d_ws;
  ushort_t* state = train + N;
  float* G = (float*)(state + N);            // ~35.6MB ws total

  prep_kernel<<<8192, 256, 0, stream>>>(x, noise, a1, train, state);
  gram_kernel<<<2048, 256, 0, stream>>>(train, state, G);
  ff_kernel<<<dim3(512, 4), 256, 0, stream>>>(x, a2, Wproj, ffa, ffb, ffg, ffe, out);
  scan_kernel<<<256, 256, 0, stream>>>(train, state, G, Wttt, out);
}

// Round 3
// 1977.078 us; speedup vs baseline: 2.1328x; 1.2375x over previous
//
#include <hip/hip_runtime.h>

typedef unsigned short ushort_t;
typedef unsigned int uint32;

#define SB 16
#define SS 2048
#define SD 256
#define KAPPA 4.8828125e-6f   // 0.01 * 2/(16*256)

__device__ __forceinline__ ushort_t f2bf(float f) {
  uint32 u = __float_as_uint(f);
  u = (u + 0x7FFFu + ((u >> 16) & 1u)) >> 16;
  return (ushort_t)u;
}
__device__ __forceinline__ float blo(uint32 u) { return __uint_as_float(u << 16); }
__device__ __forceinline__ float bhi(uint32 u) { return __uint_as_float(u & 0xFFFF0000u); }

// ---------------- prep: train/state (bf16, [t][b][d] layout) ----------------
__global__ __launch_bounds__(256) void prep_kernel(
    const float* __restrict__ x, const float* __restrict__ noise,
    const float* __restrict__ a1,
    ushort_t* __restrict__ train, ushort_t* __restrict__ state) {
  size_t i4 = (size_t)blockIdx.x * 256 + threadIdx.x;  // one float4
  size_t base = i4 * 4;
  int d = (int)(base & 255);
  int t = (int)((base >> 8) & 2047);
  int b = (int)(base >> 19);
  float4 xv = *(const float4*)(x + base);
  float4 nv = *(const float4*)(noise + base);
  float4 av = *(const float4*)(a1 + d);
  float m0 = tanhf(av.x * xv.x);
  float m1 = tanhf(av.y * xv.y);
  float m2 = tanhf(av.z * xv.z);
  float m3 = tanhf(av.w * xv.w);
  size_t dst = ((size_t)t * SB + b) * SD + d;
  ushort4 tr, st;
  tr.x = f2bf(m0 + nv.x); tr.y = f2bf(m1 + nv.y);
  tr.z = f2bf(m2 + nv.z); tr.w = f2bf(m3 + nv.w);
  st.x = f2bf(m0); st.y = f2bf(m1); st.z = f2bf(m2); st.w = f2bf(m3);
  *(ushort4*)(train + dst) = tr;
  *(ushort4*)(state + dst) = st;
}

// ---------------- gram: G[t][b][b'] = state_t[b] . train_t[b'] ----------------
__global__ __launch_bounds__(256) void gram_kernel(
    const ushort_t* __restrict__ train, const ushort_t* __restrict__ state,
    float* __restrict__ G) {
  __shared__ float Tr[16][260];
  __shared__ float St[16][260];
  const int t = blockIdx.x;
  const int tid = threadIdx.x;
#pragma unroll
  for (int v = 0; v < 2; ++v) {
    int flat8 = tid + v * 256;           // 0..511
    int b = flat8 >> 5;
    int d8 = (flat8 & 31) * 8;
    uint4 tv = *(const uint4*)(train + ((size_t)t * SB + b) * SD + d8);
    uint4 sv = *(const uint4*)(state + ((size_t)t * SB + b) * SD + d8);
    uint32 tw[4] = {tv.x, tv.y, tv.z, tv.w};
    uint32 sw[4] = {sv.x, sv.y, sv.z, sv.w};
#pragma unroll
    for (int e = 0; e < 4; ++e) {
      Tr[b][d8 + 2 * e]     = blo(tw[e]);
      Tr[b][d8 + 2 * e + 1] = bhi(tw[e]);
      St[b][d8 + 2 * e]     = blo(sw[e]);
      St[b][d8 + 2 * e + 1] = bhi(sw[e]);
    }
  }
  __syncthreads();
  int b = tid >> 4, bp = tid & 15;
  float s = 0.f;
#pragma unroll 8
  for (int k = 0; k < 256; k += 4) {
    float4 sv = *(const float4*)&St[b][k];
    float4 tv = *(const float4*)&Tr[bp][k];
    s += sv.x * tv.x + sv.y * tv.y + sv.z * tv.z + sv.w * tv.w;
  }
  G[(size_t)t * 256 + tid] = s;
}

// ---------------- ff path: out = u .* (v @ Wp^T) ----------------
__global__ __launch_bounds__(256) void ff_kernel(
    const float* __restrict__ x, const float* __restrict__ a2,
    const float* __restrict__ Wp, const float* __restrict__ ffa,
    const float* __restrict__ ffb, const float* __restrict__ ffg_,
    const float* __restrict__ ffe_, float* __restrict__ out) {
  __shared__ float As[32][68];
  __shared__ float Bs[32][68];
  const int tid = threadIdx.x;
  const int gm0 = blockIdx.x * 64;
  const int gn0 = blockIdx.y * 64;
  const int tm = tid & 15, tn = tid >> 4;
  const int lr = tid & 63;
  const int lq = tid >> 6;
  float acc[4][4];
#pragma unroll
  for (int i = 0; i < 4; i++)
#pragma unroll
    for (int j = 0; j < 4; j++) acc[i][j] = 0.f;

  for (int k0 = 0; k0 < 256; k0 += 32) {
    {
      const float* xp = x + (size_t)(gm0 + lr) * 256 + k0 + lq * 8;
      float4 v0 = *(const float4*)(xp);
      float4 v1 = *(const float4*)(xp + 4);
      const float* ap = a2 + k0 + lq * 8;
      float4 a0 = *(const float4*)(ap);
      float4 a1v = *(const float4*)(ap + 4);
      As[lq * 8 + 0][lr] = tanhf(a0.x * v0.x);
      As[lq * 8 + 1][lr] = tanhf(a0.y * v0.y);
      As[lq * 8 + 2][lr] = tanhf(a0.z * v0.z);
      As[lq * 8 + 3][lr] = tanhf(a0.w * v0.w);
      As[lq * 8 + 4][lr] = tanhf(a1v.x * v1.x);
      As[lq * 8 + 5][lr] = tanhf(a1v.y * v1.y);
      As[lq * 8 + 6][lr] = tanhf(a1v.z * v1.z);
      As[lq * 8 + 7][lr] = tanhf(a1v.w * v1.w);
      const float* wp = Wp + (size_t)(gn0 + lr) * 256 + k0 + lq * 8;
      float4 w0 = *(const float4*)(wp);
      float4 w1 = *(const float4*)(wp + 4);
      Bs[lq * 8 + 0][lr] = w0.x; Bs[lq * 8 + 1][lr] = w0.y;
      Bs[lq * 8 + 2][lr] = w0.z; Bs[lq * 8 + 3][lr] = w0.w;
      Bs[lq * 8 + 4][lr] = w1.x; Bs[lq * 8 + 5][lr] = w1.y;
      Bs[lq * 8 + 6][lr] = w1.z; Bs[lq * 8 + 7][lr] = w1.w;
    }
    __syncthreads();
#pragma unroll
    for (int k = 0; k < 32; ++k) {
      float4 av4 = *(const float4*)&As[k][tm * 4];
      float4 bv4 = *(const float4*)&Bs[k][tn * 4];
      float a[4] = {av4.x, av4.y, av4.z, av4.w};
      float b[4] = {bv4.x, bv4.y, bv4.z, bv4.w};
#pragma unroll
      for (int i = 0; i < 4; i++)
#pragma unroll
        for (int j = 0; j < 4; j++) acc[i][j] += a[i] * b[j];
    }
    __syncthreads();
  }
  const float ga = ffg_[0], et = ffe_[0];
#pragma unroll
  for (int ii = 0; ii < 4; ++ii) {
    int row = gm0 + tm * 4 + ii;
    int col = gn0 + tn * 4;
    float4 xv = *(const float4*)(x + (size_t)row * 256 + col);
    float4 fa = *(const float4*)(ffa + col);
    float4 fb = *(const float4*)(ffb + col);
    float4 a2v = *(const float4*)(a2 + col);
    float xs[4] = {xv.x, xv.y, xv.z, xv.w};
    float fas[4] = {fa.x, fa.y, fa.z, fa.w};
    float fbs[4] = {fb.x, fb.y, fb.z, fb.w};
    float a2s[4] = {a2v.x, a2v.y, a2v.z, a2v.w};
    float res[4];
#pragma unroll
    for (int j = 0; j < 4; ++j) {
      float v = tanhf(a2s[j] * xs[j]);
      float z = fas[j] * v;
      float gelu = 0.5f * z * (1.0f + erff(z * 0.70710678118654752f));
      float u = ga * gelu + et * sinf(fbs[j] * v);
      res[j] = u * acc[ii][j];
    }
    float4 o; o.x = res[0]; o.y = res[1]; o.z = res[2]; o.w = res[3];
    *(float4*)(out + (size_t)row * 256 + col) = o;
  }
}

// ---------------- scan: 256 WGs, one W row each ----------------
// phase A: P[j] = X_j . w  (X from regs, w broadcast from padded LDS, shfl reduce)
// phase B: w[k] -= kappa * sum_b diff[b] * train[b][k]   (waves 2-3, 2 cols/thread)
// phase C: out[b] = Q[b] - kappa * sum_b' G[t][b][b'] * diff[b']  (wave 0, G in regs)
__global__ __launch_bounds__(256, 1) void scan_kernel(
    const ushort_t* __restrict__ train, const ushort_t* __restrict__ state,
    const float* __restrict__ G, const float* __restrict__ Wttt,
    float* __restrict__ out) {
  __shared__ ushort_t XsT[2][16 * 264];        // train rows only, pitch 264 ushorts (132 words)
  __shared__ float wrowP[8 * 36];              // W row, 32-float chunks padded to 36 (bank-staggered)
  __shared__ alignas(16) float diffv[16];
  __shared__ alignas(16) float Qv[16];
  __shared__ float Obuf[16][16];               // [step%16][b]

  const int tid = threadIdx.x;
  const int bx = blockIdx.x;
  // XCD-aware swizzle: 32 consecutive out-columns per XCD
  const int row = ((bx & 7) << 5) | (bx >> 3);

  wrowP[((tid >> 5) * 36) + (tid & 31)] = Wttt[(size_t)row * SD + tid];

  const int srow = tid >> 3;   // 0..31: X row held in regs by this thread
  const int kg   = tid & 7;    // 32-element k-chunk
  const ushort_t* xbase = (srow < 16 ? train : state) +
                          ((size_t)(srow & 15)) * SD + kg * 32;
  const int gq = tid >> 4;     // for G regs (tid<64)
  const int gb = tid & 15;

  // prefetch t=0
  uint4 c0, c1, c2, c3;
  float4 gc;
  ushort_t sownc = 0;
  {
    const uint4* gp = (const uint4*)(xbase);
    c0 = gp[0]; c1 = gp[1]; c2 = gp[2]; c3 = gp[3];
    if (tid < 64) gc = *(const float4*)(G + gb * 16 + gq * 4);
    if (kg == 0 && srow < 16) sownc = state[(size_t)srow * SD + row];
  }

  for (int t = 0; t < SS; ++t) {
    const int buf = t & 1;
    // ---- stage train rows into LDS (raw bf16, waves 0-1) ----
    if (srow < 16) {
      ushort_t* d = &XsT[buf][srow * 264 + kg * 32];
      *(uint4*)(d)      = c0;
      *(uint4*)(d + 8)  = c1;
      *(uint4*)(d + 16) = c2;
      *(uint4*)(d + 24) = c3;
    }
    // ---- prefetch t+1 ----
    uint4 n0, n1, n2, n3;
    float4 gn;
    ushort_t sownn = 0;
    {
      const int tn_ = (t + 1 < SS) ? (t + 1) : 0;
      const uint4* gp = (const uint4*)(xbase + (size_t)tn_ * (SB * SD));
      n0 = gp[0]; n1 = gp[1]; n2 = gp[2]; n3 = gp[3];
      if (tid < 64) gn = *(const float4*)(G + (size_t)tn_ * 256 + gb * 16 + gq * 4);
      if (kg == 0 && srow < 16) sownn = state[((size_t)tn_ * SB + srow) * SD + row];
    }
    __syncthreads();  // b1: staging + W(t-1) update visible

    // ---- phase A: P[srow] over own 32 k's; X in regs, w broadcast reads ----
    {
      const uint32 U[16] = {c0.x, c0.y, c0.z, c0.w, c1.x, c1.y, c1.z, c1.w,
                            c2.x, c2.y, c2.z, c2.w, c3.x, c3.y, c3.z, c3.w};
      float a0 = 0.f, a1 = 0.f, a2 = 0.f, a3 = 0.f;
      const float* wp = &wrowP[kg * 36];
#pragma unroll
      for (int j = 0; j < 8; ++j) {
        float4 w = *(const float4*)(wp + j * 4);
        uint32 u0 = U[2 * j], u1 = U[2 * j + 1];
        a0 += blo(u0) * w.x; a1 += bhi(u0) * w.y;
        a2 += blo(u1) * w.z; a3 += bhi(u1) * w.w;
      }
      float s = (a0 + a1) + (a2 + a3);
      s += __shfl_xor(s, 1, 64);
      s += __shfl_xor(s, 2, 64);
      s += __shfl_xor(s, 4, 64);
      if (kg == 0) {
        if (srow < 16) diffv[srow] = s - __uint_as_float((uint32)sownc << 16);
        else           Qv[srow - 16] = s;
      }
    }
    __syncthreads();  // b2: diff/Q ready

    if (tid >= 128) {
      // ---- phase B: waves 2-3, thread updates W columns 2cp, 2cp+1 ----
      const int cp = tid - 128;
      float4 d0 = *(const float4*)&diffv[0];
      float4 d1 = *(const float4*)&diffv[4];
      float4 d2 = *(const float4*)&diffv[8];
      float4 d3 = *(const float4*)&diffv[12];
      const float dv[16] = {d0.x, d0.y, d0.z, d0.w, d1.x, d1.y, d1.z, d1.w,
                            d2.x, d2.y, d2.z, d2.w, d3.x, d3.y, d3.z, d3.w};
      const uint32* xw = (const uint32*)&XsT[buf][0];
      float s0 = 0.f, s1 = 0.f;
#pragma unroll
      for (int b = 0; b < 16; ++b) {
        uint32 u = xw[b * 132 + cp];
        s0 += dv[b] * blo(u);
        s1 += dv[b] * bhi(u);
      }
      float* wp2 = &wrowP[(cp >> 4) * 36 + 2 * (cp & 15)];
      wp2[0] -= KAPPA * s0;
      wp2[1] -= KAPPA * s1;
    } else if (tid < 64) {
      // ---- phase C: wave 0, G in regs ----
      float4 dq = *(const float4*)&diffv[gq * 4];
      float s = gc.x * dq.x + gc.y * dq.y + gc.z * dq.z + gc.w * dq.w;
      s += __shfl_xor(s, 16, 64);
      s += __shfl_xor(s, 32, 64);
      if (gq == 0) Obuf[t & 15][gb] = Qv[gb] - KAPPA * s;
    }

    // ---- dump 16 steps of outputs (add onto ff-path values) ----
    if ((t & 15) == 15) {
      __syncthreads();  // b3 (1/16 steps): Obuf complete
      int s_ = tid >> 4, b = tid & 15;
      size_t oi = ((size_t)b * SS + (size_t)(t - 15 + s_)) * SD + row;
      out[oi] += Obuf[s_][b];
    }

    c0 = n0; c1 = n1; c2 = n2; c3 = n3;
    gc = gn;
    sownc = sownn;
  }
}

extern "C" void kernel_launch(void* const* d_in, const int* in_sizes, int n_in,
                              void* d_out, int out_size, void* d_ws, size_t ws_size,
                              hipStream_t stream) {
  const float* x     = (const float*)d_in[0];
  const float* noise = (const float*)d_in[1];
  const float* a1    = (const float*)d_in[2];
  const float* a2    = (const float*)d_in[3];
  const float* Wttt  = (const float*)d_in[4];
  const float* Wproj = (const float*)d_in[5];
  const float* ffa   = (const float*)d_in[6];
  const float* ffb   = (const float*)d_in[7];
  const float* ffg   = (const float*)d_in[8];
  const float* ffe   = (const float*)d_in[9];
  float* out = (float*)d_out;

  const size_t N = (size_t)SB * SS * SD;     // 8388608
  ushort_t* train = (ushort_t*)d_ws;
  ushort_t* state = train + N;
  float* G = (float*)(state + N);            // ~35.6MB ws total

  prep_kernel<<<8192, 256, 0, stream>>>(x, noise, a1, train, state);
  gram_kernel<<<2048, 256, 0, stream>>>(train, state, G);
  ff_kernel<<<dim3(512, 4), 256, 0, stream>>>(x, a2, Wproj, ffa, ffb, ffg, ffe, out);
  scan_kernel<<<256, 256, 0, stream>>>(train, state, G, Wttt, out);
}